// Round 2
// baseline (226.962 us; speedup 1.0000x reference)
//
#include <hip/hip_runtime.h>
#include <hip/hip_bf16.h>

// MHA forward.  B=1, S=2048, H=1024, NH=16, DK=64.
// Inputs fp32, output fp32.  Internal bf16 MFMA pipeline, fp32 accum.
// Quirk: masked scores -> 0 (not -inf) BEFORE softmax; |scores| <= ~2 so
// softmax needs no max subtraction (m=0) and KV-split partials add.
// R9: attn rewritten: 32 q-rows/wave (2x arithmetic intensity per LDS byte),
// z=4 KV split (NITA=8, grid still 512 = 2/CU), XOR-swizzled Ks/Vs
// (pre-swizzled global source + swizzled b128 reads -> conflict-free),
// transposed mask bitfield (dwordx4 loads), exp2 with log2e folded into
// the Q scale.  partO z0-z2 alias dead Xbf, z3 + partL alias dead Wq/Wk/Wv.
// R10: identical resubmit -- R9 bench was an infra failure (container), no
// counters returned; audit found no hang/fault path.

#define S_LEN 2048
#define HID   1024
#define NHEAD 16
#define DK    64

typedef unsigned short u16;
typedef __attribute__((ext_vector_type(8))) short bf16x8;
typedef __attribute__((ext_vector_type(4))) short bf16x4;
typedef __attribute__((ext_vector_type(4))) float f32x4;
typedef __attribute__((ext_vector_type(4))) unsigned u32x4;

__device__ __forceinline__ void load16_lds(const void* g, void* l) {
  __builtin_amdgcn_global_load_lds(
      (const __attribute__((address_space(1))) void*)g,
      (__attribute__((address_space(3))) void*)l, 16, 0, 0);
}

__device__ __forceinline__ short bfbits(float x) {
  __hip_bfloat16 h = __float2bfloat16(x);
  return *(short*)&h;
}
__device__ __forceinline__ bf16x8 cvt8(float4 a, float4 b) {
  bf16x8 r;
  r[0] = bfbits(a.x); r[1] = bfbits(a.y); r[2] = bfbits(a.z); r[3] = bfbits(a.w);
  r[4] = bfbits(b.x); r[5] = bfbits(b.y); r[6] = bfbits(b.z); r[7] = bfbits(b.w);
  return r;
}
__device__ __forceinline__ float bf2f(u16 u) {
  unsigned v = (unsigned)u << 16;
  return *(float*)&v;
}

// ---------------------------------------------------------------------------
// 0. convert q,k,v (2M elems each) + Wq,Wk,Wv,Wo (1M each) fp32 -> bf16.
// ---------------------------------------------------------------------------
__global__ __launch_bounds__(256) void cvt_kernel(
    const float* __restrict__ q, const float* __restrict__ k,
    const float* __restrict__ v, const float* __restrict__ wq,
    const float* __restrict__ wk, const float* __restrict__ wv,
    const float* __restrict__ wo, u16* __restrict__ Xbf,
    u16* __restrict__ Wbf) {
  const int y = blockIdx.y;
  size_t i = ((size_t)blockIdx.x * 256 + threadIdx.x) * 8;
  const float* src;
  u16* dst;
  size_t n;
  if (y < 3) {
    src = y == 0 ? q : (y == 1 ? k : v);
    dst = Xbf + (size_t)y * (S_LEN * HID);
    n = (size_t)S_LEN * HID;
  } else {
    int w = y - 3;
    src = w == 0 ? wq : (w == 1 ? wk : (w == 2 ? wv : wo));
    dst = Wbf + (size_t)w * (HID * HID);
    n = (size_t)HID * HID;
  }
  if (i >= n) return;
  float4 a = *(const float4*)(src + i);
  float4 b = *(const float4*)(src + i + 4);
  *(bf16x8*)(dst + i) = cvt8(a, b);
}

// ---------------------------------------------------------------------------
// 1. pack attention_mask (S x S int32 0/1) -> TRANSPOSED bitmask:
//    bitsT[widx][row], widx = kv>>5.  Lets attn load 4 consecutive rows'
//    words as one dwordx4.  row-fast thread order -> coalesced writes;
//    reads are 128B-chunky strided (read-once, fine).
// ---------------------------------------------------------------------------
__global__ __launch_bounds__(256) void pack_mask_kernel(
    const int* __restrict__ mask, unsigned int* __restrict__ bitsT) {
  int idx = blockIdx.x * 256 + threadIdx.x;   // 0 .. 2048*64-1
  int row = idx & 2047, widx = idx >> 11;
  const int4* p = (const int4*)(mask + (size_t)row * S_LEN + widx * 32);
  unsigned word = 0;
#pragma unroll
  for (int i = 0; i < 8; ++i) {
    int4 v = p[i];
    word |= (unsigned)(v.x != 0) << (i * 4 + 0);
    word |= (unsigned)(v.y != 0) << (i * 4 + 1);
    word |= (unsigned)(v.z != 0) << (i * 4 + 2);
    word |= (unsigned)(v.w != 0) << (i * 4 + 3);
  }
  bitsT[(size_t)widx * S_LEN + row] = word;
}

// ---------------------------------------------------------------------------
// 2. QKV GEMM: Y = X @ W^T + b.  BM=64, BN=128, BK=64, 256 thr / 4 waves,
//    wave tile 64x32.  grid 256 x/z3 = 768 blocks = 3/CU.  All-async bf16
//    staging, dbuf.  z=0: Y *= 0.125*log2(e) -> Qb (exp2 fold);
//    z=1 -> Kb ; z=2 -> Vt transposed.
// ---------------------------------------------------------------------------
__global__ __launch_bounds__(256) void gemm_qkv(
    const u16* __restrict__ Xbf, const u16* __restrict__ Wbf,
    const float* __restrict__ bq, const float* __restrict__ bk,
    const float* __restrict__ bv, u16* __restrict__ Qb,
    u16* __restrict__ Kb, u16* __restrict__ Vt) {
  constexpr int Mm = 2048, Nn = 1024, Kk = 1024, NIT = 16;
  const int z = blockIdx.z;
  const u16* A = Xbf + (size_t)z * (S_LEN * HID);
  const u16* W = Wbf + (size_t)z * (HID * HID);
  const float* bias = z == 0 ? bq : (z == 1 ? bk : bv);
  u16* C = z == 0 ? Qb : (z == 1 ? Kb : Vt);
  // 0.125 (1/sqrt(dk)) * log2(e): attn uses exp2 directly.
  const float oscale = (z == 0) ? 0.125f * 1.44269504088896f : 1.0f;
  const int transpose = (z == 2);

  const int tid = threadIdx.x, lane = tid & 63, wave = tid >> 6;
  const int q4 = lane >> 4, c16 = lane & 15;
  const int bx = blockIdx.x;
  const int mBase = (bx & 31) * 64;    // same-XCD blocks share A rows
  const int nBase = (bx >> 5) * 128;
  const int wn = wave * 32;

  __shared__ __align__(16) u16 As[2][2][64 * 32];
  __shared__ __align__(16) u16 Bs[2][2][128 * 32];

  f32x4 acc[4][2] = {};
  const int srow = lane >> 2, se8 = (lane & 3) * 8;

  auto issue = [&](int it, int buf) {
#pragma unroll
    for (int j = 0; j < 2; ++j) {      // A: 8 units of 1 KB
      int u = wave * 2 + j, h = u >> 2, grp = u & 3;
      load16_lds(A + (size_t)(mBase + grp * 16 + srow) * Kk + it * 64 +
                     h * 32 + se8,
                 &As[buf][h][grp * 512]);
    }
#pragma unroll
    for (int j = 0; j < 4; ++j) {      // B: 16 units
      int u = wave * 4 + j, h = u >> 3, grp = u & 7;
      load16_lds(W + (size_t)(nBase + grp * 16 + srow) * Kk + it * 64 +
                     h * 32 + se8,
                 &Bs[buf][h][grp * 512]);
    }
  };

  issue(0, 0);
  __syncthreads();

  for (int it = 0; it < NIT; ++it) {
    const int buf = it & 1, nbuf = buf ^ 1;
    if (it + 1 < NIT) issue(it + 1, nbuf);
#pragma unroll
    for (int kk = 0; kk < 2; ++kk) {
      bf16x8 af[4], bfr[2];
#pragma unroll
      for (int t = 0; t < 4; ++t)
        af[t] = *(const bf16x8*)&As[buf][kk][(t * 16 + c16) * 32 + q4 * 8];
#pragma unroll
      for (int t = 0; t < 2; ++t)
        bfr[t] = *(const bf16x8*)&Bs[buf][kk][(wn + t * 16 + c16) * 32 + q4 * 8];
#pragma unroll
      for (int mt = 0; mt < 4; ++mt)
#pragma unroll
        for (int nt = 0; nt < 2; ++nt)
          acc[mt][nt] = __builtin_amdgcn_mfma_f32_16x16x32_bf16(
              af[mt], bfr[nt], acc[mt][nt], 0, 0, 0);
    }
    __syncthreads();
  }

#pragma unroll
  for (int nt = 0; nt < 2; ++nt) {
    int col = nBase + wn + nt * 16 + c16;
    float bv2 = bias[col];
#pragma unroll
    for (int mt = 0; mt < 4; ++mt) {
#pragma unroll
      for (int r = 0; r < 4; ++r) {
        int row = mBase + mt * 16 + q4 * 4 + r;
        float v = (acc[mt][nt][r] + bv2) * oscale;
        if (transpose)
          ((__hip_bfloat16*)C)[(size_t)col * Mm + row] = __float2bfloat16(v);
        else
          ((__hip_bfloat16*)C)[(size_t)row * Nn + col] = __float2bfloat16(v);
      }
    }
  }
}

// ---------------------------------------------------------------------------
// 3. Attention.  8 waves x 32 q-rows (256 rows/block), KV-split z=4,
//    NITA=8.  Ks/Vs XOR-swizzled (src-slot ^ row&3 on stage, q4 ^ c16&3 on
//    read) -> conflict-free ds_read_b128.  Mask via transposed bitfield,
//    dwordx4 per 4 rows.  Softmax = single v_exp (log2e pre-folded in Q).
//    LDS 68KB/block -> 2 blocks/CU; launch_bounds caps VGPR<=128 for
//    16 waves/CU residency.
// ---------------------------------------------------------------------------
__global__ __launch_bounds__(512, 4) void attn_kernel(
    const u16* __restrict__ Qb, const u16* __restrict__ Kb,
    const u16* __restrict__ Vt, const unsigned* __restrict__ mbT,
    u16* __restrict__ partOA, u16* __restrict__ partO3,
    float* __restrict__ partL) {
  constexpr int NITA = 8;                       // 512 kv / 64
  const int qt = blockIdx.x, h = blockIdx.y, zz = blockIdx.z;
  const int tid = threadIdx.x, lane = tid & 63, wave = tid >> 6;
  const int q4 = lane >> 4, c16 = lane & 15;

  __shared__ __align__(16) u16 Ks[2][2][64 * 32];
  __shared__ __align__(16) u16 Vs[2][2][64 * 32];
  __shared__ __align__(16) u16 Ps[8][32 * 72];

  const int q0 = qt * 256 + wave * 32;

  bf16x8 qf[2][2];
#pragma unroll
  for (int m = 0; m < 2; ++m)
#pragma unroll
    for (int kk = 0; kk < 2; ++kk)
      qf[m][kk] = *(const bf16x8*)(Qb + (size_t)(q0 + m * 16 + c16) * HID +
                                   h * DK + kk * 32 + q4 * 8);

  f32x4 o[2][4] = {};
  float l_lane[2][4] = {{}, {}};
  const unsigned mlo = 1u << c16, mhi = mlo << 16;

  const int srow = lane >> 2;
  const int sslot = ((lane & 3) ^ (srow & 3)) * 8;   // pre-swizzled src slot
  const int kvbase = zz * (S_LEN / 4);

  auto issueKV = [&](int it, int buf) {
    const int kv0 = kvbase + it * 64;
#pragma unroll
    for (int j = 0; j < 2; ++j) {
      int i = wave * 2 + j;          // 0..15
      if (i < 8) {
        int half = i >> 2, grp = i & 3;
        load16_lds(Kb + (size_t)(kv0 + grp * 16 + srow) * HID + h * DK +
                       half * 32 + sslot,
                   &Ks[buf][half][grp * 512]);
      } else {
        int ii = i - 8;
        int half = ii >> 2, grp = ii & 3;
        load16_lds(Vt + (size_t)(h * DK + grp * 16 + srow) * S_LEN + kv0 +
                       half * 32 + sslot,
                   &Vs[buf][half][grp * 512]);
      }
    }
  };

  issueKV(0, 0);
  __syncthreads();

  __hip_bfloat16* pw = (__hip_bfloat16*)&Ps[wave][0];

  for (int it = 0; it < NITA; ++it) {
    const int buf = it & 1, nbuf = buf ^ 1;
    if (it + 1 < NITA) issueKV(it + 1, nbuf);

    // mask words for this 64-kv stripe: dwordx4 covers rows r=0..3.
    const unsigned* mr = mbT + (size_t)(zz * 16 + it * 2) * S_LEN + q0 + q4 * 4;
    u32x4 mwa[2][2];
#pragma unroll
    for (int m = 0; m < 2; ++m) {
      mwa[m][0] = *(const u32x4*)(mr + m * 16);
      mwa[m][1] = *(const u32x4*)(mr + S_LEN + m * 16);
    }

#pragma unroll
    for (int nt = 0; nt < 4; ++nt) {
      const int rsw = (nt * 16 + c16) * 32 + ((q4 ^ (c16 & 3)) * 8);
      bf16x8 kf0 = *(const bf16x8*)&Ks[buf][0][rsw];
      bf16x8 kf1 = *(const bf16x8*)&Ks[buf][1][rsw];
#pragma unroll
      for (int m = 0; m < 2; ++m) {
        f32x4 a = {};
        a = __builtin_amdgcn_mfma_f32_16x16x32_bf16(qf[m][0], kf0, a, 0, 0, 0);
        a = __builtin_amdgcn_mfma_f32_16x16x32_bf16(qf[m][1], kf1, a, 0, 0, 0);
#pragma unroll
        for (int r = 0; r < 4; ++r) {
          unsigned word = mwa[m][nt >> 1][r];
          unsigned keep = word & ((nt & 1) ? mhi : mlo);
          float s = keep ? a[r] : 0.0f;
          float p = exp2f(s);                  // log2e folded into Q scale
          l_lane[m][r] += p;
          pw[(m * 16 + q4 * 4 + r) * 72 + nt * 16 + c16] = __float2bfloat16(p);
        }
      }
    }

    asm volatile("s_waitcnt lgkmcnt(0)" ::: "memory");

#pragma unroll
    for (int kk = 0; kk < 2; ++kk) {
      bf16x8 pa0 = *(const bf16x8*)&Ps[wave][(c16) * 72 + kk * 32 + q4 * 8];
      bf16x8 pa1 = *(const bf16x8*)&Ps[wave][(16 + c16) * 72 + kk * 32 + q4 * 8];
#pragma unroll
      for (int nt = 0; nt < 4; ++nt) {
        const int rsw = (nt * 16 + c16) * 32 + ((q4 ^ (c16 & 3)) * 8);
        bf16x8 vb = *(const bf16x8*)&Vs[buf][kk][rsw];
        o[0][nt] = __builtin_amdgcn_mfma_f32_16x16x32_bf16(pa0, vb, o[0][nt], 0, 0, 0);
        o[1][nt] = __builtin_amdgcn_mfma_f32_16x16x32_bf16(pa1, vb, o[1][nt], 0, 0, 0);
      }
    }
    __syncthreads();
  }

  u16* pO = (zz < 3) ? (partOA + (size_t)zz * (S_LEN * HID)) : partO3;
#pragma unroll
  for (int m = 0; m < 2; ++m)
#pragma unroll
    for (int r = 0; r < 4; ++r) {
      float s = l_lane[m][r];
#pragma unroll
      for (int d = 1; d < 16; d <<= 1) s += __shfl_xor(s, d);
      int row = q0 + m * 16 + q4 * 4 + r;
#pragma unroll
      for (int nt = 0; nt < 4; ++nt)
        ((__hip_bfloat16*)pO)[(size_t)row * HID + h * DK + nt * 16 + c16] =
            __float2bfloat16(o[m][nt][r]);
      if (c16 == 0)
        partL[((size_t)zz * NHEAD + h) * S_LEN + row] = s;
    }
}

// ---------------------------------------------------------------------------
// 4. combine 4 KV-split partials: ctx = (O0+O1+O2+O3) / (l0+l1+l2+l3), bf16.
// ---------------------------------------------------------------------------
__global__ __launch_bounds__(256) void combine_kernel(
    const u16* __restrict__ pOA, const u16* __restrict__ pO3,
    const float* __restrict__ partL, u16* __restrict__ ctx) {
  size_t idx = ((size_t)blockIdx.x * 256 + threadIdx.x) * 4;
  int row = (int)(idx >> 10);
  int col = (int)(idx & 1023);
  int h = col >> 6;
  float l = 0.0f;
#pragma unroll
  for (int z = 0; z < 4; ++z)
    l += partL[((size_t)z * NHEAD + h) * S_LEN + row];
  float inv = 1.0f / l;
  bf16x4 a0 = *(const bf16x4*)(pOA + idx);
  bf16x4 a1 = *(const bf16x4*)(pOA + (size_t)S_LEN * HID + idx);
  bf16x4 a2 = *(const bf16x4*)(pOA + 2 * (size_t)S_LEN * HID + idx);
  bf16x4 a3 = *(const bf16x4*)(pO3 + idx);
  bf16x4 r;
#pragma unroll
  for (int j = 0; j < 4; ++j) {
    float v = (bf2f((u16)a0[j]) + bf2f((u16)a1[j]) + bf2f((u16)a2[j]) +
               bf2f((u16)a3[j])) * inv;
    r[j] = bfbits(v);
  }
  *(bf16x4*)(ctx + idx) = r;
}

// ---------------------------------------------------------------------------
// 5. Output GEMM: out = ctx @ Wo^T + bo, fp32 store.  BM=32, BN=128 ->
//    grid 512 = 2/CU.  256 thr / 4 waves, wave tile 32x32.
// ---------------------------------------------------------------------------
__global__ __launch_bounds__(256) void gemm_out(
    const u16* __restrict__ ctx, const u16* __restrict__ Wo,
    const float* __restrict__ bo, float* __restrict__ out) {
  constexpr int Nn = 1024, Kk = 1024, NIT = 16;
  const int tid = threadIdx.x, lane = tid & 63, wave = tid >> 6;
  const int q4 = lane >> 4, c16 = lane & 15;
  const int bx = blockIdx.x;
  const int mBase = (bx & 63) * 32;    // same-XCD blocks share A rows
  const int nBase = (bx >> 6) * 128;
  const int wn = wave * 32;

  __shared__ __align__(16) u16 As[2][2][32 * 32];
  __shared__ __align__(16) u16 Bs[2][2][128 * 32];

  f32x4 acc[2][2] = {};
  const int srow = lane >> 2, se8 = (lane & 3) * 8;

  auto issue = [&](int it, int buf) {
    {                                   // A: 4 units, 1/wave
      int u = wave, h = u >> 1, grp = u & 1;
      load16_lds(ctx + (size_t)(mBase + grp * 16 + srow) * Kk + it * 64 +
                     h * 32 + se8,
                 &As[buf][h][grp * 512]);
    }
#pragma unroll
    for (int j = 0; j < 4; ++j) {       // B: 16 units
      int u = wave * 4 + j, h = u >> 3, grp = u & 7;
      load16_lds(Wo + (size_t)(nBase + grp * 16 + srow) * Kk + it * 64 +
                     h * 32 + se8,
                 &Bs[buf][h][grp * 512]);
    }
  };

  issue(0, 0);
  __syncthreads();

  for (int it = 0; it < NIT; ++it) {
    const int buf = it & 1, nbuf = buf ^ 1;
    if (it + 1 < NIT) issue(it + 1, nbuf);
#pragma unroll
    for (int kk = 0; kk < 2; ++kk) {
      bf16x8 af[2], bfr[2];
#pragma unroll
      for (int t = 0; t < 2; ++t)
        af[t] = *(const bf16x8*)&As[buf][kk][(t * 16 + c16) * 32 + q4 * 8];
#pragma unroll
      for (int t = 0; t < 2; ++t)
        bfr[t] = *(const bf16x8*)&Bs[buf][kk][(wn + t * 16 + c16) * 32 + q4 * 8];
#pragma unroll
      for (int mt = 0; mt < 2; ++mt)
#pragma unroll
        for (int nt = 0; nt < 2; ++nt)
          acc[mt][nt] = __builtin_amdgcn_mfma_f32_16x16x32_bf16(
              af[mt], bfr[nt], acc[mt][nt], 0, 0, 0);
    }
    __syncthreads();
  }

#pragma unroll
  for (int nt = 0; nt < 2; ++nt) {
    int col = nBase + wn + nt * 16 + c16;
    float bv = bo[col];
#pragma unroll
    for (int mt = 0; mt < 2; ++mt)
#pragma unroll
      for (int r = 0; r < 4; ++r) {
        int row = mBase + mt * 16 + q4 * 4 + r;
        out[(size_t)row * Nn + col] = acc[mt][nt][r] + bv;
      }
  }
}

// ---------------------------------------------------------------------------
extern "C" void kernel_launch(void* const* d_in, const int* in_sizes, int n_in,
                              void* d_out, int out_size, void* d_ws, size_t ws_size,
                              hipStream_t stream) {
  const float* q    = (const float*)d_in[0];
  const float* k    = (const float*)d_in[1];
  const float* v    = (const float*)d_in[2];
  const int*   mask = (const int*)d_in[3];
  const float* Wq = (const float*)d_in[4];
  const float* bq = (const float*)d_in[5];
  const float* Wk = (const float*)d_in[6];
  const float* bk = (const float*)d_in[7];
  const float* Wv = (const float*)d_in[8];
  const float* bv = (const float*)d_in[9];
  const float* Wo = (const float*)d_in[10];
  const float* bo = (const float*)d_in[11];

  const size_t M2 = (size_t)S_LEN * HID;          // 2M elems
  const size_t W1 = (size_t)HID * HID;            // 1M elems
  // Wbf 4M | Xbf 6M | Qb 2M (->ctx) | Kb 2M | Vt 2M | mbits | (legacy partL)
  // After gemm_qkv: Xbf dead -> partO z0..z2; Wq/Wk dead -> partO z3;
  // Wv dead -> partL (4*NHEAD*S floats = 512KB <= 2MB).
  const size_t need = (4 * W1 + 3 * M2 + 3 * M2) * 2 +
                      (size_t)S_LEN * 64 * 4 + 2 * NHEAD * S_LEN * 4;
  if (ws_size < need) return;   // diagnostic: absmax==0.0752 -> ws too small

  u16* Wbf = (u16*)d_ws;                  // 4M elems
  u16* Xbf = Wbf + 4 * W1;                // 6M elems (q,k,v bf16)
  u16* Qb = Xbf + 3 * M2;
  u16* Kb = Qb + M2;
  u16* Vt = Kb + M2;
  unsigned* mbits = (unsigned*)(Vt + M2);
  u16* partOA = Xbf;                      // z0..z2 (6M elems, X dead)
  u16* partO3 = Wbf;                      // z3 (Wq+Wk dead)
  float* partL = (float*)(Wbf + 2 * W1);  // Wv region dead
  u16* ctx = Qb;   // Qb dead after attn

  hipLaunchKernelGGL(cvt_kernel, dim3(1024, 7), dim3(256), 0, stream,
                     q, k, v, Wq, Wk, Wv, Wo, Xbf, Wbf);

  hipLaunchKernelGGL(pack_mask_kernel, dim3((S_LEN * (S_LEN / 32)) / 256),
                     dim3(256), 0, stream, mask, mbits);

  hipLaunchKernelGGL(gemm_qkv, dim3(256, 1, 3), dim3(256), 0, stream,
                     Xbf, Wbf, bq, bk, bv, Qb, Kb, Vt);

  hipLaunchKernelGGL(attn_kernel, dim3(S_LEN / 256, NHEAD, 4), dim3(512), 0,
                     stream, Qb, Kb, Vt, mbits, partOA, partO3, partL);

  hipLaunchKernelGGL(combine_kernel, dim3((S_LEN * HID / 4) / 256), dim3(256),
                     0, stream, partOA, partO3, partL, ctx);

  hipLaunchKernelGGL(gemm_out, dim3(512), dim3(256), 0, stream,
                     ctx, Wbf + 3 * W1, bo, (float*)d_out);
}

// Round 3
// 206.631 us; speedup vs baseline: 1.0984x; 1.0984x over previous
//
#include <hip/hip_runtime.h>
#include <hip/hip_bf16.h>

// MHA forward.  B=1, S=2048, H=1024, NH=16, DK=64.
// Inputs fp32, output fp32.  Internal bf16 MFMA pipeline, fp32 accum.
// Quirk: masked scores -> 0 (not -inf) BEFORE softmax; |scores| <= ~2 so
// softmax needs no max subtraction (m=0) and KV-split partials add.
// R11: fixes for R9's measured regressions:
//  - XCD-aware work remap (attn + both GEMMs): blocks sharing K/V (or W)
//    panels now co-locate on one XCD L2 (R9 FETCH 86MB was 8x K/V refetch).
//  - LDS slot-XOR corrected to ^((row>>1)&3)  (R9's ^(row&3) left 4-way
//    conflicts; this gives 2-way = free per m136).
//  - P stored packed (col' = kk*32 + c16*2 + (nt&1)): 16 free b32 writes
//    replace 32 conflicted b16 writes; Vt rows pre-permuted in gemm_qkv
//    (p(v) = (v&15)*2 + v>>4 within 32-row groups) so PV k-order matches.

#define S_LEN 2048
#define HID   1024
#define NHEAD 16
#define DK    64

typedef unsigned short u16;
typedef __attribute__((ext_vector_type(8))) short bf16x8;
typedef __attribute__((ext_vector_type(4))) short bf16x4;
typedef __attribute__((ext_vector_type(4))) float f32x4;
typedef __attribute__((ext_vector_type(4))) unsigned u32x4;

__device__ __forceinline__ void load16_lds(const void* g, void* l) {
  __builtin_amdgcn_global_load_lds(
      (const __attribute__((address_space(1))) void*)g,
      (__attribute__((address_space(3))) void*)l, 16, 0, 0);
}

__device__ __forceinline__ short bfbits(float x) {
  __hip_bfloat16 h = __float2bfloat16(x);
  return *(short*)&h;
}
__device__ __forceinline__ bf16x8 cvt8(float4 a, float4 b) {
  bf16x8 r;
  r[0] = bfbits(a.x); r[1] = bfbits(a.y); r[2] = bfbits(a.z); r[3] = bfbits(a.w);
  r[4] = bfbits(b.x); r[5] = bfbits(b.y); r[6] = bfbits(b.z); r[7] = bfbits(b.w);
  return r;
}
__device__ __forceinline__ float bf2f(u16 u) {
  unsigned v = (unsigned)u << 16;
  return *(float*)&v;
}

// ---------------------------------------------------------------------------
// 0. convert q,k,v (2M elems each) + Wq,Wk,Wv,Wo (1M each) fp32 -> bf16.
// ---------------------------------------------------------------------------
__global__ __launch_bounds__(256) void cvt_kernel(
    const float* __restrict__ q, const float* __restrict__ k,
    const float* __restrict__ v, const float* __restrict__ wq,
    const float* __restrict__ wk, const float* __restrict__ wv,
    const float* __restrict__ wo, u16* __restrict__ Xbf,
    u16* __restrict__ Wbf) {
  const int y = blockIdx.y;
  size_t i = ((size_t)blockIdx.x * 256 + threadIdx.x) * 8;
  const float* src;
  u16* dst;
  size_t n;
  if (y < 3) {
    src = y == 0 ? q : (y == 1 ? k : v);
    dst = Xbf + (size_t)y * (S_LEN * HID);
    n = (size_t)S_LEN * HID;
  } else {
    int w = y - 3;
    src = w == 0 ? wq : (w == 1 ? wk : (w == 2 ? wv : wo));
    dst = Wbf + (size_t)w * (HID * HID);
    n = (size_t)HID * HID;
  }
  if (i >= n) return;
  float4 a = *(const float4*)(src + i);
  float4 b = *(const float4*)(src + i + 4);
  *(bf16x8*)(dst + i) = cvt8(a, b);
}

// ---------------------------------------------------------------------------
// 1. pack attention_mask (S x S int32 0/1) -> TRANSPOSED bitmask:
//    bitsT[widx][row], widx = kv>>5.
// ---------------------------------------------------------------------------
__global__ __launch_bounds__(256) void pack_mask_kernel(
    const int* __restrict__ mask, unsigned int* __restrict__ bitsT) {
  int idx = blockIdx.x * 256 + threadIdx.x;   // 0 .. 2048*64-1
  int row = idx & 2047, widx = idx >> 11;
  const int4* p = (const int4*)(mask + (size_t)row * S_LEN + widx * 32);
  unsigned word = 0;
#pragma unroll
  for (int i = 0; i < 8; ++i) {
    int4 v = p[i];
    word |= (unsigned)(v.x != 0) << (i * 4 + 0);
    word |= (unsigned)(v.y != 0) << (i * 4 + 1);
    word |= (unsigned)(v.z != 0) << (i * 4 + 2);
    word |= (unsigned)(v.w != 0) << (i * 4 + 3);
  }
  bitsT[(size_t)widx * S_LEN + row] = word;
}

// ---------------------------------------------------------------------------
// 2. QKV GEMM: Y = X @ W^T + b.  BM=64, BN=128, BK=64, 256 thr / 4 waves,
//    wave tile 64x32.  grid 256 x/z3 = 768 blocks = 3/CU.
//    XCD chunking: each XCD owns an 8mG x 4nG region (A+B panel locality).
//    z=0: Y *= 0.125*log2(e) -> Qb ; z=1 -> Kb ; z=2 -> Vt transposed with
//    kv rows permuted within 32-groups (p(v) = (v&15)*2 + v>>4) for attn PV.
// ---------------------------------------------------------------------------
__global__ __launch_bounds__(256) void gemm_qkv(
    const u16* __restrict__ Xbf, const u16* __restrict__ Wbf,
    const float* __restrict__ bq, const float* __restrict__ bk,
    const float* __restrict__ bv, u16* __restrict__ Qb,
    u16* __restrict__ Kb, u16* __restrict__ Vt) {
  constexpr int Mm = 2048, Nn = 1024, Kk = 1024, NIT = 16;
  const int z = blockIdx.z;
  const u16* A = Xbf + (size_t)z * (S_LEN * HID);
  const u16* W = Wbf + (size_t)z * (HID * HID);
  const float* bias = z == 0 ? bq : (z == 1 ? bk : bv);
  u16* C = z == 0 ? Qb : (z == 1 ? Kb : Vt);
  const float oscale = (z == 0) ? 0.125f * 1.44269504088896f : 1.0f;
  const int transpose = (z == 2);

  const int tid = threadIdx.x, lane = tid & 63, wave = tid >> 6;
  const int q4 = lane >> 4, c16 = lane & 15;
  // XCD chunking: xcd = bx&7 owns mGroups (xcd>>1)*8+[0,8), nGroups (xcd&1)*4+[0,4)
  const int bx = blockIdx.x;
  const int xcd = bx & 7, sIdx = bx >> 3;
  const int mBase = ((xcd >> 1) * 8 + (sIdx & 7)) * 64;
  const int nBase = ((xcd & 1) * 4 + (sIdx >> 3)) * 128;
  const int wn = wave * 32;

  __shared__ __align__(16) u16 As[2][2][64 * 32];
  __shared__ __align__(16) u16 Bs[2][2][128 * 32];

  f32x4 acc[4][2] = {};
  const int srow = lane >> 2;
  const int sx8 = ((lane & 3) ^ ((srow >> 1) & 3)) * 8;   // staging slot-XOR
  const int rx8 = (q4 ^ ((c16 >> 1) & 3)) * 8;            // read slot-XOR

  auto issue = [&](int it, int buf) {
#pragma unroll
    for (int j = 0; j < 2; ++j) {      // A: 8 units of 1 KB
      int u = wave * 2 + j, h = u >> 2, grp = u & 3;
      load16_lds(A + (size_t)(mBase + grp * 16 + srow) * Kk + it * 64 +
                     h * 32 + sx8,
                 &As[buf][h][grp * 512]);
    }
#pragma unroll
    for (int j = 0; j < 4; ++j) {      // B: 16 units
      int u = wave * 4 + j, h = u >> 3, grp = u & 7;
      load16_lds(W + (size_t)(nBase + grp * 16 + srow) * Kk + it * 64 +
                     h * 32 + sx8,
                 &Bs[buf][h][grp * 512]);
    }
  };

  issue(0, 0);
  __syncthreads();

  for (int it = 0; it < NIT; ++it) {
    const int buf = it & 1, nbuf = buf ^ 1;
    if (it + 1 < NIT) issue(it + 1, nbuf);
#pragma unroll
    for (int kk = 0; kk < 2; ++kk) {
      bf16x8 af[4], bfr[2];
#pragma unroll
      for (int t = 0; t < 4; ++t)
        af[t] = *(const bf16x8*)&As[buf][kk][(t * 16 + c16) * 32 + rx8];
#pragma unroll
      for (int t = 0; t < 2; ++t)
        bfr[t] = *(const bf16x8*)&Bs[buf][kk][(wn + t * 16 + c16) * 32 + rx8];
#pragma unroll
      for (int mt = 0; mt < 4; ++mt)
#pragma unroll
        for (int nt = 0; nt < 2; ++nt)
          acc[mt][nt] = __builtin_amdgcn_mfma_f32_16x16x32_bf16(
              af[mt], bfr[nt], acc[mt][nt], 0, 0, 0);
    }
    __syncthreads();
  }

#pragma unroll
  for (int nt = 0; nt < 2; ++nt) {
    int col = nBase + wn + nt * 16 + c16;
    float bv2 = bias[col];
#pragma unroll
    for (int mt = 0; mt < 4; ++mt) {
#pragma unroll
      for (int r = 0; r < 4; ++r) {
        int row = mBase + mt * 16 + q4 * 4 + r;
        float v = (acc[mt][nt][r] + bv2) * oscale;
        if (transpose) {
          // permute kv rows within 32-groups so attn's packed-P k-order
          // matches: position p holds kv (p&1)*16 + (p>>1).
          int vv = row & 31;
          int rowp = (row & ~31) | (((vv & 15) << 1) | (vv >> 4));
          ((__hip_bfloat16*)C)[(size_t)col * Mm + rowp] = __float2bfloat16(v);
        } else {
          ((__hip_bfloat16*)C)[(size_t)row * Nn + col] = __float2bfloat16(v);
        }
      }
    }
  }
}

// ---------------------------------------------------------------------------
// 3. Attention.  8 waves x 32 q-rows (256 rows/block), KV-split z=4, NITA=8.
//    XCD remap: work = (lin&7)*64 + lin>>3 -> each XCD owns 8 (h,zz) groups
//    x all 8 qt (K/V fetched once per XCD).  Ks/Vs slot-XOR ^((row>>1)&3)
//    -> 2-way (free).  P packed: col' = kk*32 + c16*2 + (nt&1); 16 b32
//    writes (conflict-free), PV reads match Vt's permuted kv order.
// ---------------------------------------------------------------------------
__global__ __launch_bounds__(512, 4) void attn_kernel(
    const u16* __restrict__ Qb, const u16* __restrict__ Kb,
    const u16* __restrict__ Vt, const unsigned* __restrict__ mbT,
    u16* __restrict__ partOA, u16* __restrict__ partO3,
    float* __restrict__ partL) {
  constexpr int NITA = 8;                       // 512 kv / 64
  const int lin = blockIdx.x + 8 * (blockIdx.y + 16 * blockIdx.z);
  const int work = ((lin & 7) << 6) | (lin >> 3);
  const int qt = work & 7, h = (work >> 3) & 15, zz = work >> 7;
  const int tid = threadIdx.x, lane = tid & 63, wave = tid >> 6;
  const int q4 = lane >> 4, c16 = lane & 15;

  __shared__ __align__(16) u16 Ks[2][2][64 * 32];
  __shared__ __align__(16) u16 Vs[2][2][64 * 32];
  __shared__ __align__(16) u16 Ps[8][32 * 72];

  const int q0 = qt * 256 + wave * 32;

  bf16x8 qf[2][2];
#pragma unroll
  for (int m = 0; m < 2; ++m)
#pragma unroll
    for (int kk = 0; kk < 2; ++kk)
      qf[m][kk] = *(const bf16x8*)(Qb + (size_t)(q0 + m * 16 + c16) * HID +
                                   h * DK + kk * 32 + q4 * 8);

  f32x4 o[2][4] = {};
  float l_lane[2][4] = {{}, {}};
  const unsigned mlo = 1u << c16, mhi = mlo << 16;

  const int srow = lane >> 2;
  const int sx8 = ((lane & 3) ^ ((srow >> 1) & 3)) * 8;   // staging slot-XOR
  const int rx8 = (q4 ^ ((c16 >> 1) & 3)) * 8;            // read slot-XOR
  const int kvbase = zz * (S_LEN / 4);

  auto issueKV = [&](int it, int buf) {
    const int kv0 = kvbase + it * 64;
#pragma unroll
    for (int j = 0; j < 2; ++j) {
      int i = wave * 2 + j;          // 0..15
      if (i < 8) {
        int half = i >> 2, grp = i & 3;
        load16_lds(Kb + (size_t)(kv0 + grp * 16 + srow) * HID + h * DK +
                       half * 32 + sx8,
                   &Ks[buf][half][grp * 512]);
      } else {
        int ii = i - 8;
        int half = ii >> 2, grp = ii & 3;
        load16_lds(Vt + (size_t)(h * DK + grp * 16 + srow) * S_LEN + kv0 +
                       half * 32 + sx8,
                   &Vs[buf][half][grp * 512]);
      }
    }
  };

  issueKV(0, 0);
  __syncthreads();

  u16* pw = &Ps[wave][0];

  for (int it = 0; it < NITA; ++it) {
    const int buf = it & 1, nbuf = buf ^ 1;
    if (it + 1 < NITA) issueKV(it + 1, nbuf);

    // mask words for this 64-kv stripe: dwordx4 covers rows r=0..3.
    const unsigned* mr = mbT + (size_t)(zz * 16 + it * 2) * S_LEN + q0 + q4 * 4;
    u32x4 mwa[2][2];
#pragma unroll
    for (int m = 0; m < 2; ++m) {
      mwa[m][0] = *(const u32x4*)(mr + m * 16);
      mwa[m][1] = *(const u32x4*)(mr + S_LEN + m * 16);
    }

    // QK^T: all 8 score fragments first (K reads 2-way conflict-free).
    f32x4 sv[2][4];
#pragma unroll
    for (int nt = 0; nt < 4; ++nt) {
      const int rsw = (nt * 16 + c16) * 32 + rx8;
      bf16x8 kf0 = *(const bf16x8*)&Ks[buf][0][rsw];
      bf16x8 kf1 = *(const bf16x8*)&Ks[buf][1][rsw];
#pragma unroll
      for (int m = 0; m < 2; ++m) {
        f32x4 a = {};
        a = __builtin_amdgcn_mfma_f32_16x16x32_bf16(qf[m][0], kf0, a, 0, 0, 0);
        a = __builtin_amdgcn_mfma_f32_16x16x32_bf16(qf[m][1], kf1, a, 0, 0, 0);
        sv[m][nt] = a;
      }
    }

    // mask -> exp2 -> row-sum; then pack P pairs (nt even/odd) as b32.
#pragma unroll
    for (int m = 0; m < 2; ++m)
#pragma unroll
      for (int r = 0; r < 4; ++r) {
#pragma unroll
        for (int nt = 0; nt < 4; ++nt) {
          unsigned word = mwa[m][nt >> 1][r];
          unsigned keep = word & ((nt & 1) ? mhi : mlo);
          float s = keep ? sv[m][nt][r] : 0.0f;
          float p = exp2f(s);                  // log2e folded into Q scale
          sv[m][nt][r] = p;
          l_lane[m][r] += p;
        }
        int prow = m * 16 + q4 * 4 + r;
#pragma unroll
        for (int kkp = 0; kkp < 2; ++kkp) {
          unsigned lo = (unsigned)(u16)bfbits(sv[m][2 * kkp][r]);
          unsigned hi = (unsigned)(u16)bfbits(sv[m][2 * kkp + 1][r]);
          *(unsigned*)&pw[prow * 72 + kkp * 32 + c16 * 2] = lo | (hi << 16);
        }
      }

    asm volatile("s_waitcnt lgkmcnt(0)" ::: "memory");

#pragma unroll
    for (int kk = 0; kk < 2; ++kk) {
      bf16x8 pa0 = *(const bf16x8*)&pw[(c16) * 72 + kk * 32 + q4 * 8];
      bf16x8 pa1 = *(const bf16x8*)&pw[(16 + c16) * 72 + kk * 32 + q4 * 8];
#pragma unroll
      for (int nt = 0; nt < 4; ++nt) {
        const int rsw = (nt * 16 + c16) * 32 + rx8;
        bf16x8 vb = *(const bf16x8*)&Vs[buf][kk][rsw];
        o[0][nt] = __builtin_amdgcn_mfma_f32_16x16x32_bf16(pa0, vb, o[0][nt], 0, 0, 0);
        o[1][nt] = __builtin_amdgcn_mfma_f32_16x16x32_bf16(pa1, vb, o[1][nt], 0, 0, 0);
      }
    }
    __syncthreads();
  }

  u16* pO = (zz < 3) ? (partOA + (size_t)zz * (S_LEN * HID)) : partO3;
#pragma unroll
  for (int m = 0; m < 2; ++m)
#pragma unroll
    for (int r = 0; r < 4; ++r) {
      float s = l_lane[m][r];
#pragma unroll
      for (int d = 1; d < 16; d <<= 1) s += __shfl_xor(s, d);
      int row = q0 + m * 16 + q4 * 4 + r;
#pragma unroll
      for (int nt = 0; nt < 4; ++nt)
        ((__hip_bfloat16*)pO)[(size_t)row * HID + h * DK + nt * 16 + c16] =
            __float2bfloat16(o[m][nt][r]);
      if (c16 == 0)
        partL[((size_t)zz * NHEAD + h) * S_LEN + row] = s;
    }
}

// ---------------------------------------------------------------------------
// 4. combine 4 KV-split partials: ctx = (O0+O1+O2+O3) / (l0+l1+l2+l3), bf16.
// ---------------------------------------------------------------------------
__global__ __launch_bounds__(256) void combine_kernel(
    const u16* __restrict__ pOA, const u16* __restrict__ pO3,
    const float* __restrict__ partL, u16* __restrict__ ctx) {
  size_t idx = ((size_t)blockIdx.x * 256 + threadIdx.x) * 4;
  int row = (int)(idx >> 10);
  int col = (int)(idx & 1023);
  int h = col >> 6;
  float l = 0.0f;
#pragma unroll
  for (int z = 0; z < 4; ++z)
    l += partL[((size_t)z * NHEAD + h) * S_LEN + row];
  float inv = 1.0f / l;
  bf16x4 a0 = *(const bf16x4*)(pOA + idx);
  bf16x4 a1 = *(const bf16x4*)(pOA + (size_t)S_LEN * HID + idx);
  bf16x4 a2 = *(const bf16x4*)(pOA + 2 * (size_t)S_LEN * HID + idx);
  bf16x4 a3 = *(const bf16x4*)(pO3 + idx);
  bf16x4 r;
#pragma unroll
  for (int j = 0; j < 4; ++j) {
    float v = (bf2f((u16)a0[j]) + bf2f((u16)a1[j]) + bf2f((u16)a2[j]) +
               bf2f((u16)a3[j])) * inv;
    r[j] = bfbits(v);
  }
  *(bf16x4*)(ctx + idx) = r;
}

// ---------------------------------------------------------------------------
// 5. Output GEMM: out = ctx @ Wo^T + bo, fp32 store.  BM=32, BN=128 ->
//    grid 512 = 2/CU.  XCD chunking 16mG x 4nG.  Slot-XOR LDS.
// ---------------------------------------------------------------------------
__global__ __launch_bounds__(256) void gemm_out(
    const u16* __restrict__ ctx, const u16* __restrict__ Wo,
    const float* __restrict__ bo, float* __restrict__ out) {
  constexpr int Nn = 1024, Kk = 1024, NIT = 16;
  const int tid = threadIdx.x, lane = tid & 63, wave = tid >> 6;
  const int q4 = lane >> 4, c16 = lane & 15;
  const int bx = blockIdx.x;
  const int xcd = bx & 7, sIdx = bx >> 3;           // sIdx 0..63
  const int mBase = ((xcd >> 1) * 16 + (sIdx & 15)) * 32;
  const int nBase = ((xcd & 1) * 4 + (sIdx >> 4)) * 128;
  const int wn = wave * 32;

  __shared__ __align__(16) u16 As[2][2][32 * 32];
  __shared__ __align__(16) u16 Bs[2][2][128 * 32];

  f32x4 acc[2][2] = {};
  const int srow = lane >> 2;
  const int sx8 = ((lane & 3) ^ ((srow >> 1) & 3)) * 8;
  const int rx8 = (q4 ^ ((c16 >> 1) & 3)) * 8;

  auto issue = [&](int it, int buf) {
    {                                   // A: 4 units, 1/wave
      int u = wave, h = u >> 1, grp = u & 1;
      load16_lds(ctx + (size_t)(mBase + grp * 16 + srow) * Kk + it * 64 +
                     h * 32 + sx8,
                 &As[buf][h][grp * 512]);
    }
#pragma unroll
    for (int j = 0; j < 4; ++j) {       // B: 16 units
      int u = wave * 4 + j, h = u >> 3, grp = u & 7;
      load16_lds(Wo + (size_t)(nBase + grp * 16 + srow) * Kk + it * 64 +
                     h * 32 + sx8,
                 &Bs[buf][h][grp * 512]);
    }
  };

  issue(0, 0);
  __syncthreads();

  for (int it = 0; it < NIT; ++it) {
    const int buf = it & 1, nbuf = buf ^ 1;
    if (it + 1 < NIT) issue(it + 1, nbuf);
#pragma unroll
    for (int kk = 0; kk < 2; ++kk) {
      bf16x8 af[2], bfr[2];
#pragma unroll
      for (int t = 0; t < 2; ++t)
        af[t] = *(const bf16x8*)&As[buf][kk][(t * 16 + c16) * 32 + rx8];
#pragma unroll
      for (int t = 0; t < 2; ++t)
        bfr[t] = *(const bf16x8*)&Bs[buf][kk][(wn + t * 16 + c16) * 32 + rx8];
#pragma unroll
      for (int mt = 0; mt < 2; ++mt)
#pragma unroll
        for (int nt = 0; nt < 2; ++nt)
          acc[mt][nt] = __builtin_amdgcn_mfma_f32_16x16x32_bf16(
              af[mt], bfr[nt], acc[mt][nt], 0, 0, 0);
    }
    __syncthreads();
  }

#pragma unroll
  for (int nt = 0; nt < 2; ++nt) {
    int col = nBase + wn + nt * 16 + c16;
    float bv = bo[col];
#pragma unroll
    for (int mt = 0; mt < 2; ++mt)
#pragma unroll
      for (int r = 0; r < 4; ++r) {
        int row = mBase + mt * 16 + q4 * 4 + r;
        out[(size_t)row * Nn + col] = acc[mt][nt][r] + bv;
      }
  }
}

// ---------------------------------------------------------------------------
extern "C" void kernel_launch(void* const* d_in, const int* in_sizes, int n_in,
                              void* d_out, int out_size, void* d_ws, size_t ws_size,
                              hipStream_t stream) {
  const float* q    = (const float*)d_in[0];
  const float* k    = (const float*)d_in[1];
  const float* v    = (const float*)d_in[2];
  const int*   mask = (const int*)d_in[3];
  const float* Wq = (const float*)d_in[4];
  const float* bq = (const float*)d_in[5];
  const float* Wk = (const float*)d_in[6];
  const float* bk = (const float*)d_in[7];
  const float* Wv = (const float*)d_in[8];
  const float* bv = (const float*)d_in[9];
  const float* Wo = (const float*)d_in[10];
  const float* bo = (const float*)d_in[11];

  const size_t M2 = (size_t)S_LEN * HID;          // 2M elems
  const size_t W1 = (size_t)HID * HID;            // 1M elems
  // Wbf 4M | Xbf 6M | Qb 2M (->ctx) | Kb 2M | Vt 2M | mbits | (legacy partL)
  // After gemm_qkv: Xbf dead -> partO z0..z2; Wq/Wk dead -> partO z3;
  // Wv dead -> partL.
  const size_t need = (4 * W1 + 3 * M2 + 3 * M2) * 2 +
                      (size_t)S_LEN * 64 * 4 + 2 * NHEAD * S_LEN * 4;
  if (ws_size < need) return;   // diagnostic: absmax==0.0752 -> ws too small

  u16* Wbf = (u16*)d_ws;                  // 4M elems
  u16* Xbf = Wbf + 4 * W1;                // 6M elems (q,k,v bf16)
  u16* Qb = Xbf + 3 * M2;
  u16* Kb = Qb + M2;
  u16* Vt = Kb + M2;
  unsigned* mbits = (unsigned*)(Vt + M2);
  u16* partOA = Xbf;                      // z0..z2 (6M elems, X dead)
  u16* partO3 = Wbf;                      // z3 (Wq+Wk dead)
  float* partL = (float*)(Wbf + 2 * W1);  // Wv region dead
  u16* ctx = Qb;   // Qb dead after attn

  hipLaunchKernelGGL(cvt_kernel, dim3(1024, 7), dim3(256), 0, stream,
                     q, k, v, Wq, Wk, Wv, Wo, Xbf, Wbf);

  hipLaunchKernelGGL(pack_mask_kernel, dim3((S_LEN * (S_LEN / 32)) / 256),
                     dim3(256), 0, stream, mask, mbits);

  hipLaunchKernelGGL(gemm_qkv, dim3(256, 1, 3), dim3(256), 0, stream,
                     Xbf, Wbf, bq, bk, bv, Qb, Kb, Vt);

  hipLaunchKernelGGL(attn_kernel, dim3(S_LEN / 256, NHEAD, 4), dim3(512), 0,
                     stream, Qb, Kb, Vt, mbits, partOA, partO3, partL);

  hipLaunchKernelGGL(combine_kernel, dim3((S_LEN * HID / 4) / 256), dim3(256),
                     0, stream, partOA, partO3, partL, ctx);

  hipLaunchKernelGGL(gemm_out, dim3(512), dim3(256), 0, stream,
                     ctx, Wbf + 3 * W1, bo, (float*)d_out);
}